// Round 12
// baseline (116.587 us; speedup 1.0000x reference)
//
#include <hip/hip_runtime.h>
#include <stdint.h>

// Binarized dense via i8 MFMA: C[r][u] = dot(sign(x[r,:]), sign(W[:,u])) + b[u]
// sign in {+1,-1} encoded as i8 0x01 / 0xFF; i32 accumulation is exact
// (|dot| <= 4096). Uses v_mfma_i32_32x32x32_i8 (A/B = v4i32 = 16 i8, K=32).
//
// Layouts:
//  - Wb (workspace, 2 MB): W packed i8, K-step-blocked: byte[(s*512+n)*64+k']
//    where s = k/64, k' = k%64. B-tile for step s = one contiguous 32 KB run.
//  - mm_kernel: 256 blocks x 512 thr (8 waves). Block = 64 rows x 512 cols
//    (x read from HBM exactly once). Wave wv owns cols wv*64..+63 = 2x2
//    mfma C-tiles (acc 64 VGPR). K-loop: 64 steps of K=64, LDS dbuf
//    (A 2x64x80 + B 2x512x80 = 90 KB), ONE barrier/step, reg-prefetch of
//    next A(f32)+B(i8) issued before compute (T14).
//  - frag maps (32x32x32): A row = l&31, k = (l>>5)*16+[0..15] (byte order
//    ascending k); B col = l&31, same k; C/D col = l&31,
//    row = (r&3)+8*(r>>2)+4*(l>>5)  [guide m74/m101 verified].
//  - pad-80 rows: frag b128 reads hit all 8 bank-groups uniformly (5r mod 8
//    is a full cycle) -> conflict-free.

#define BATCH  16384
#define UNITS  512
#define KDIM   4096
#define KSTEP  64
#define NSTEP  (KDIM / KSTEP)   // 64
#define APAD   80
#define BPAD   80

typedef int v4i  __attribute__((ext_vector_type(4)));
typedef int v16i __attribute__((ext_vector_type(16)));

// ---- pack W: f32 [4096][512] -> Wb i8 +/-1, K-step-blocked (2 MB) ----------
__global__ __launch_bounds__(256) void pack_w_kernel(const float* __restrict__ W,
                                                     unsigned long long* __restrict__ Wb) {
    int t  = blockIdx.x * 256 + threadIdx.x;   // 0..262143
    int n  = t & 511;                          // col (wave-contiguous -> coalesced reads)
    int k0 = (t >> 9) * 8;                     // 8 consecutive k
    unsigned long long m = 0;
    #pragma unroll
    for (int j = 0; j < 8; ++j) {
        float v = W[(size_t)(k0 + j) * UNITS + n];
        m |= ((v < 0.f) ? 0xFFull : 0x01ull) << (8 * j);
    }
    // byte addr ((k0>>6)*512 + n)*64 + (k0&63)  (8B-aligned)
    Wb[((size_t)(k0 >> 6) * 512 + n) * 8 + ((k0 & 63) >> 3)] = m;
}

__device__ __forceinline__ uint32_t sgn4(float4 v) {
    uint32_t b0 = v.x < 0.f ? 0xFFu : 0x01u;
    uint32_t b1 = v.y < 0.f ? 0xFFu : 0x01u;
    uint32_t b2 = v.z < 0.f ? 0xFFu : 0x01u;
    uint32_t b3 = v.w < 0.f ? 0xFFu : 0x01u;
    return b0 | (b1 << 8) | (b2 << 16) | (b3 << 24);
}

// ------------------------------- MFMA GEMM ----------------------------------
__global__ __launch_bounds__(512, 1) void mm_kernel(const float* __restrict__ x,
                                                    const uint8_t* __restrict__ Wb,
                                                    const float* __restrict__ bias,
                                                    float* __restrict__ C) {
    __shared__ __attribute__((aligned(16))) uint8_t Alds[2][64][APAD];   // 12.5 KB
    __shared__ __attribute__((aligned(16))) uint8_t Blds[2][512][BPAD];  // 80 KB
    const int t  = threadIdx.x;
    const int l  = t & 63;
    const int wv = t >> 6;          // wave 0..7 -> cols wv*64..+63
    const int row0 = blockIdx.x * 64;
    const int ar = t >> 3;          // A staging row 0..63
    const int ak = (t & 7) * 8;     // A staging k-offset (8 floats)
    const int lr = l & 31;          // lane row/col within 32x32 tile
    const int lk = (l >> 5) * 16;   // lane k-offset within K=32

    v16i acc[2][2];
    #pragma unroll
    for (int a = 0; a < 2; ++a)
        #pragma unroll
        for (int b = 0; b < 2; ++b)
            #pragma unroll
            for (int e = 0; e < 16; ++e) acc[a][b][e] = 0;

    // ---- prologue: stage step 0 ----
    {
        const float* xs = x + (size_t)(row0 + ar) * KDIM + ak;
        float4 a0 = *reinterpret_cast<const float4*>(xs);
        float4 a1 = *reinterpret_cast<const float4*>(xs + 4);
        #pragma unroll
        for (int q = 0; q < 4; ++q) {
            int c = t + 512 * q;    // 0..2047: col = c>>2, 16B-chunk = c&3
            v4i bv = *reinterpret_cast<const v4i*>(Wb + (size_t)(c >> 2) * 64 + (c & 3) * 16);
            *reinterpret_cast<v4i*>(&Blds[0][c >> 2][(c & 3) * 16]) = bv;
        }
        *reinterpret_cast<uint32_t*>(&Alds[0][ar][ak])     = sgn4(a0);
        *reinterpret_cast<uint32_t*>(&Alds[0][ar][ak + 4]) = sgn4(a1);
        __syncthreads();
    }

    #pragma unroll 1
    for (int s = 0; s < NSTEP; ++s) {
        const int buf = s & 1, nbf = buf ^ 1;
        const bool pf = (s + 1 < NSTEP);
        float4 a0, a1;
        v4i br[4];

        // ---- issue next-step loads (stay in flight under compute) ----
        if (pf) {
            const float* xs = x + (size_t)(row0 + ar) * KDIM + (s + 1) * KSTEP + ak;
            a0 = *reinterpret_cast<const float4*>(xs);
            a1 = *reinterpret_cast<const float4*>(xs + 4);
            const uint8_t* bsrc = Wb + (size_t)(s + 1) * (512 * 64);
            #pragma unroll
            for (int q = 0; q < 4; ++q) {
                int c = t + 512 * q;
                br[q] = *reinterpret_cast<const v4i*>(bsrc + (size_t)(c >> 2) * 64 + (c & 3) * 16);
            }
        }

        // ---- compute step s from LDS[buf] ----
        #pragma unroll
        for (int ks = 0; ks < 2; ++ks) {
            v4i af[2], bf[2];
            #pragma unroll
            for (int rt = 0; rt < 2; ++rt)
                af[rt] = *reinterpret_cast<const v4i*>(
                    &Alds[buf][rt * 32 + lr][ks * 32 + lk]);
            #pragma unroll
            for (int ct = 0; ct < 2; ++ct)
                bf[ct] = *reinterpret_cast<const v4i*>(
                    &Blds[buf][wv * 64 + ct * 32 + lr][ks * 32 + lk]);
            #pragma unroll
            for (int rt = 0; rt < 2; ++rt)
                #pragma unroll
                for (int ct = 0; ct < 2; ++ct)
                    acc[rt][ct] = __builtin_amdgcn_mfma_i32_32x32x32_i8(
                        af[rt], bf[ct], acc[rt][ct], 0, 0, 0);
        }

        // ---- commit prefetch to LDS[nbf] (convert x to +/-1 i8) ----
        if (pf) {
            #pragma unroll
            for (int q = 0; q < 4; ++q) {
                int c = t + 512 * q;
                *reinterpret_cast<v4i*>(&Blds[nbf][c >> 2][(c & 3) * 16]) = br[q];
            }
            *reinterpret_cast<uint32_t*>(&Alds[nbf][ar][ak])     = sgn4(a0);
            *reinterpret_cast<uint32_t*>(&Alds[nbf][ar][ak + 4]) = sgn4(a1);
        }
        __syncthreads();
    }

    // ---- epilogue: C = acc + bias ----
    #pragma unroll
    for (int ct = 0; ct < 2; ++ct) {
        const int col = wv * 64 + ct * 32 + lr;
        const float bv = bias[col];
        #pragma unroll
        for (int rt = 0; rt < 2; ++rt) {
            #pragma unroll
            for (int r = 0; r < 16; ++r) {
                int row = row0 + rt * 32 + (r & 3) + 8 * (r >> 2) + 4 * (l >> 5);
                C[(size_t)row * UNITS + col] = (float)acc[rt][ct][r] + bv;
            }
        }
    }
}

extern "C" void kernel_launch(void* const* d_in, const int* in_sizes, int n_in,
                              void* d_out, int out_size, void* d_ws, size_t ws_size,
                              hipStream_t stream) {
    const float* x = (const float*)d_in[0];
    const float* W = (const float*)d_in[1];
    const float* b = (const float*)d_in[2];
    float* out = (float*)d_out;

    unsigned long long* Wb = (unsigned long long*)d_ws;   // 2 MB packed i8 W

    pack_w_kernel<<<(512 * 512) / 256, 256, 0, stream>>>(W, Wb);
    mm_kernel<<<BATCH / 64, 512, 0, stream>>>(
        x, (const uint8_t*)Wb, b, out);
}

// Round 13
// 107.076 us; speedup vs baseline: 1.0888x; 1.0888x over previous
//
#include <hip/hip_runtime.h>
#include <stdint.h>

// Binarized dense via i8 MFMA: C[r][u] = dot(sign(x[r,:]), sign(W[:,u])) + b[u]
// sign in {+1,-1} as i8 0x01/0xFF; i32 accumulation exact (|dot| <= 4096).
// v_mfma_i32_32x32x32_i8: A/B = v4i (16 i8), lane&31 = row/col, lane>>5 =
// k-half-16; C/D: col = lane&31 (B side), row = (r&3)+8*(r>>2)+4*(lane>>5)
// -- all verified on HW by round 12 (absmax 0).
//
// v8 design (fix round 12's 1-block/CU barrier lockstep):
//  - B NEVER touches LDS. Wb2 is fragment-major: 16B chunk index
//    ((s*16 + n5)*2 + ks)*64 + lane, lane holds col n5*32+(lane&31),
//    k = s*64 + ks*32 + (lane>>5)*16 .. +15. A wave's B-fragment load is one
//    coalesced 1KB global_load_dwordx4 from L2 (Wb2 = 2MB, L2-resident),
//    double-buffered in registers (bcur/bnext, 32 VGPR).
//  - LDS holds ONLY A-fragments (4 KB): Af[buf][ks][lane*16]. Reads are
//    lane-consecutive b128 (conflict-free); sgn4 writes: 4 threads share a
//    16B granule at distinct 4B banks (conflict-free).
//  - Block = 32 rows x 512 cols; 512 blocks = 2/CU, 16 waves/CU; x read from
//    HBM exactly once; x-pipeline 2-deep (issue x(s+2) during step s).
//  - VGPR ~95 (acc 32 + bcur/bnext 32 + x 8 + af 8 + addr) < 128 cap.
// Per-CU/step: HBM 16KB=1600cy > MFMA 64x9=580cy > LDS ~400cy -> HBM-bound.

#define BATCH  16384
#define UNITS  512
#define KDIM   4096
#define KSTEP  64
#define NSTEP  (KDIM / KSTEP)   // 64
#define MROWS  32               // rows per block

typedef int v4i  __attribute__((ext_vector_type(4)));
typedef int v16i __attribute__((ext_vector_type(16)));

// ---- pack W: f32 [4096][512] -> Wb2 fragment-major i8 +/-1 (2 MB) ----------
__global__ __launch_bounds__(256) void pack_w_kernel(const float* __restrict__ W,
                                                     uint8_t* __restrict__ Wb2) {
    int t  = blockIdx.x * 256 + threadIdx.x;   // 0..262143
    int n  = t & 511;                          // col
    int k0 = (t >> 9) * 8;                     // 8 consecutive k
    unsigned long long m = 0;
    #pragma unroll
    for (int j = 0; j < 8; ++j) {
        float v = W[(size_t)(k0 + j) * UNITS + n];
        m |= ((v < 0.f) ? 0xFFull : 0x01ull) << (8 * j);
    }
    int s  = k0 >> 6;
    int kk = k0 & 63;
    int ks = kk >> 5;
    int hi = (kk & 31) >> 4;
    int lane = (n & 31) + 32 * hi;
    size_t a = ((((size_t)s * 16 + (n >> 5)) * 2 + ks) * 64 + lane) * 16 + (kk & 15);
    *reinterpret_cast<unsigned long long*>(Wb2 + a) = m;
}

__device__ __forceinline__ uint32_t sgn4(float4 v) {
    uint32_t b0 = v.x < 0.f ? 0xFFu : 0x01u;
    uint32_t b1 = v.y < 0.f ? 0xFFu : 0x01u;
    uint32_t b2 = v.z < 0.f ? 0xFFu : 0x01u;
    uint32_t b3 = v.w < 0.f ? 0xFFu : 0x01u;
    return b0 | (b1 << 8) | (b2 << 16) | (b3 << 24);
}

// ------------------------------- MFMA GEMM ----------------------------------
__global__ __launch_bounds__(512, 1) void mm_kernel(const float* __restrict__ x,
                                                    const uint8_t* __restrict__ Wb2,
                                                    const float* __restrict__ bias,
                                                    float* __restrict__ C) {
    __shared__ __attribute__((aligned(16))) uint8_t Af[2][2][64 * 16];  // 4 KB
    const int t   = threadIdx.x;
    const int l   = t & 63;
    const int wv  = t >> 6;              // wave 0..7 -> cols wv*64..+63
    const int lr  = l & 31;
    const int hi  = l >> 5;
    const int row0 = blockIdx.x * MROWS;
    // A staging: thread t -> row ar, 4 floats at k-offset ak (one float4)
    const int ar = t >> 4;               // 0..31
    const int ak = (t & 15) * 4;         // 0..60
    const int a_lane = (ar & 31) + 32 * ((ak >> 4) & 1);
    const int a_ks   = ak >> 5;
    const int a_off  = ak & 15;
    uint8_t* aw[2] = { &Af[0][a_ks][a_lane * 16 + a_off],
                       &Af[1][a_ks][a_lane * 16 + a_off] };
    const float* xrow = x + (size_t)(row0 + ar) * KDIM + ak;

    v16i acc[2];
    #pragma unroll
    for (int ct = 0; ct < 2; ++ct)
        #pragma unroll
        for (int e = 0; e < 16; ++e) acc[ct][e] = 0;

    // B fragment pointers: chunk16 = ((s*16 + wv*2+ct)*2 + ks)*64 + l
    const uint8_t* bbase = Wb2 + ((size_t)(wv * 2) * 2 * 64 + l) * 16;
    // per (ct,ks) byte offset: ((ct*2 + ks)*64)*16 ; per step: 16*2*64*16 = 32768

    float4 xcur, xnext;
    v4i bcur[4], bnext[4];

    // ---- prologue ----
    {
        float4 x0 = *reinterpret_cast<const float4*>(xrow);          // step 0
        xcur = *reinterpret_cast<const float4*>(xrow + KSTEP);       // step 1
        #pragma unroll
        for (int q = 0; q < 4; ++q)
            bcur[q] = *reinterpret_cast<const v4i*>(bbase + (size_t)q * 1024);
        *reinterpret_cast<uint32_t*>(aw[0]) = sgn4(x0);
        __syncthreads();
    }

    #pragma unroll 1
    for (int s = 0; s < NSTEP; ++s) {
        const int buf = s & 1, nbf = buf ^ 1;
        const int s1 = (s + 1 < NSTEP) ? s + 1 : NSTEP - 1;   // clamped
        const int s2 = (s + 2 < NSTEP) ? s + 2 : NSTEP - 1;

        // issue x(s+2) and B(s+1) -- stay in flight under this step
        xnext = *reinterpret_cast<const float4*>(xrow + (size_t)s2 * KSTEP);
        const uint8_t* bsrc = bbase + (size_t)s1 * 32768;
        #pragma unroll
        for (int q = 0; q < 4; ++q)
            bnext[q] = *reinterpret_cast<const v4i*>(bsrc + (size_t)q * 1024);

        // A fragments from LDS (lane-consecutive, conflict-free)
        v4i af[2];
        #pragma unroll
        for (int ks = 0; ks < 2; ++ks)
            af[ks] = *reinterpret_cast<const v4i*>(&Af[buf][ks][l * 16]);

        // MFMA: acc[ct] += A(ks) * B(ct,ks)
        #pragma unroll
        for (int ks = 0; ks < 2; ++ks)
            #pragma unroll
            for (int ct = 0; ct < 2; ++ct)
                acc[ct] = __builtin_amdgcn_mfma_i32_32x32x32_i8(
                    af[ks], bcur[ct * 2 + ks], acc[ct], 0, 0, 0);

        // commit A(s+1) = sgn4(xcur) into LDS[nbf]; rotate pipelines
        *reinterpret_cast<uint32_t*>(aw[nbf]) = sgn4(xcur);
        __syncthreads();
        xcur = xnext;
        #pragma unroll
        for (int q = 0; q < 4; ++q) bcur[q] = bnext[q];
    }

    // ---- epilogue: C = acc + bias ----
    #pragma unroll
    for (int ct = 0; ct < 2; ++ct) {
        const int col = wv * 64 + ct * 32 + lr;
        const float bv = bias[col];
        #pragma unroll
        for (int r = 0; r < 16; ++r) {
            int row = row0 + (r & 3) + 8 * (r >> 2) + 4 * hi;
            C[(size_t)row * UNITS + col] = (float)acc[ct][r] + bv;
        }
    }
}

extern "C" void kernel_launch(void* const* d_in, const int* in_sizes, int n_in,
                              void* d_out, int out_size, void* d_ws, size_t ws_size,
                              hipStream_t stream) {
    const float* x = (const float*)d_in[0];
    const float* W = (const float*)d_in[1];
    const float* b = (const float*)d_in[2];
    float* out = (float*)d_out;

    uint8_t* Wb2 = (uint8_t*)d_ws;   // 2 MB fragment-major packed W

    pack_w_kernel<<<(512 * 512) / 256, 256, 0, stream>>>(W, Wb2);
    mm_kernel<<<BATCH / MROWS, 512, 0, stream>>>(x, Wb2, b, out);
}

// Round 14
// 98.427 us; speedup vs baseline: 1.1845x; 1.0879x over previous
//
#include <hip/hip_runtime.h>
#include <stdint.h>

// Binarized dense via i8 MFMA: C[r][u] = dot(sign(x[r,:]), sign(W[:,u])) + b[u]
// sign in {+1,-1} as i8 0x01/0xFF; i32 accumulation exact (|dot| <= 4096).
// v_mfma_i32_32x32x32_i8: A/B = v4i (16 i8), lane&31 = row/col, lane>>5 =
// k-16-half; C/D: col = lane&31, row = (r&3)+8*(r>>2)+4*(lane>>5).
// All layouts/maps HW-verified (rounds 12/13, absmax 0).
//
// v9 = v8 with the per-step pipeline-rotation stalls removed:
//  - K-loop unrolled x2 with NAMED parity register sets (xp0/xp1, bp0/bp1):
//    no bcur=bnext / xcur=xnext copies -> no mid-step vmcnt drains; every
//    load is consumed 1-2 full steps after issue (x ~1.9 steps > 900cy HBM
//    latency; B ~1 step > 300cy L2 latency).
//  - A(s+1) committed at step END (sgn4 of the parity x reg), one
//    __syncthreads per step; Af write targets the buffer last read at s-1.
//  - s_setprio(1) around the MFMA cluster (T5; 2 blocks/CU phase diversity).
//  - B never touches LDS (fragment-major Wb2, coalesced 1KB wave loads from
//    L2); LDS = A-fragments only (4 KB dbuf).
// 512 blocks x 512 thr (block = 32 rows x 512 cols; x read from HBM once),
// 2 blocks/CU. VGPR ~95 (acc 32 + bp 32 + xp 8 + af 8 + addr) < 128 cap.

#define BATCH  16384
#define UNITS  512
#define KDIM   4096
#define KSTEP  64
#define NSTEP  (KDIM / KSTEP)   // 64
#define MROWS  32               // rows per block

typedef int v4i  __attribute__((ext_vector_type(4)));
typedef int v16i __attribute__((ext_vector_type(16)));

// ---- pack W: f32 [4096][512] -> Wb2 fragment-major i8 +/-1 (2 MB) ----------
// 16B chunk index ((s*16 + n5)*2 + ks)*64 + lane; lane = (n&31) + 32*k16half;
// covers col n5*32+(n&31), k = s*64 + ks*32 + k16half*16 + [0..15].
__global__ __launch_bounds__(256) void pack_w_kernel(const float* __restrict__ W,
                                                     uint8_t* __restrict__ Wb2) {
    int t  = blockIdx.x * 256 + threadIdx.x;   // 0..262143
    int n  = t & 511;                          // col
    int k0 = (t >> 9) * 8;                     // 8 consecutive k
    unsigned long long m = 0;
    #pragma unroll
    for (int j = 0; j < 8; ++j) {
        float v = W[(size_t)(k0 + j) * UNITS + n];
        m |= ((v < 0.f) ? 0xFFull : 0x01ull) << (8 * j);
    }
    int s  = k0 >> 6;
    int kk = k0 & 63;
    int ks = kk >> 5;
    int hi = (kk & 31) >> 4;
    int lane = (n & 31) + 32 * hi;
    size_t a = ((((size_t)s * 16 + (n >> 5)) * 2 + ks) * 64 + lane) * 16 + (kk & 15);
    *reinterpret_cast<unsigned long long*>(Wb2 + a) = m;
}

__device__ __forceinline__ uint32_t sgn4(float4 v) {
    uint32_t b0 = v.x < 0.f ? 0xFFu : 0x01u;
    uint32_t b1 = v.y < 0.f ? 0xFFu : 0x01u;
    uint32_t b2 = v.z < 0.f ? 0xFFu : 0x01u;
    uint32_t b3 = v.w < 0.f ? 0xFFu : 0x01u;
    return b0 | (b1 << 8) | (b2 << 16) | (b3 << 24);
}

// One K-step with compile-time parity. PBUF = Af buffer to READ (= S&1).
// XLD := x(S+2) issue; BLD := B(S+1) issue; MFMA consumes BCN = B(S);
// commit sgn4(XCM) = A(S+1) into Af[PBUF^1]; one barrier.
#define MMSTEP(S, PBUF, XLD, XCM, BLD, BCN)                                    \
    {                                                                          \
        const int cs1 = ((S) + 1 < NSTEP) ? (S) + 1 : NSTEP - 1;               \
        const int cs2 = ((S) + 2 < NSTEP) ? (S) + 2 : NSTEP - 1;               \
        XLD = *reinterpret_cast<const float4*>(xrow + (size_t)cs2 * KSTEP);    \
        const uint8_t* bsrc = bbase + (size_t)cs1 * 32768;                     \
        BLD[0] = *reinterpret_cast<const v4i*>(bsrc);                          \
        BLD[1] = *reinterpret_cast<const v4i*>(bsrc + 1024);                   \
        BLD[2] = *reinterpret_cast<const v4i*>(bsrc + 2048);                   \
        BLD[3] = *reinterpret_cast<const v4i*>(bsrc + 3072);                   \
        v4i af0 = *reinterpret_cast<const v4i*>(&Af[PBUF][0][l * 16]);         \
        v4i af1 = *reinterpret_cast<const v4i*>(&Af[PBUF][1][l * 16]);         \
        __builtin_amdgcn_s_setprio(1);                                         \
        acc0 = __builtin_amdgcn_mfma_i32_32x32x32_i8(af0, BCN[0], acc0, 0, 0, 0); \
        acc0 = __builtin_amdgcn_mfma_i32_32x32x32_i8(af1, BCN[1], acc0, 0, 0, 0); \
        acc1 = __builtin_amdgcn_mfma_i32_32x32x32_i8(af0, BCN[2], acc1, 0, 0, 0); \
        acc1 = __builtin_amdgcn_mfma_i32_32x32x32_i8(af1, BCN[3], acc1, 0, 0, 0); \
        __builtin_amdgcn_s_setprio(0);                                         \
        *reinterpret_cast<uint32_t*>(awp[(PBUF) ^ 1]) = sgn4(XCM);             \
        __syncthreads();                                                       \
    }

// ------------------------------- MFMA GEMM ----------------------------------
__global__ __launch_bounds__(512, 1) void mm_kernel(const float* __restrict__ x,
                                                    const uint8_t* __restrict__ Wb2,
                                                    const float* __restrict__ bias,
                                                    float* __restrict__ C) {
    __shared__ __attribute__((aligned(16))) uint8_t Af[2][2][64 * 16];  // 4 KB
    const int t   = threadIdx.x;
    const int l   = t & 63;
    const int wv  = t >> 6;              // wave 0..7 -> cols wv*64..+63
    const int lr  = l & 31;
    const int hi  = l >> 5;
    const int row0 = blockIdx.x * MROWS;
    // A staging: thread t -> row ar, one float4 at k-offset ak
    const int ar = t >> 4;               // 0..31
    const int ak = (t & 15) * 4;         // 0..60
    const int a_lane = (ar & 31) + 32 * ((ak >> 4) & 1);
    const int a_ks   = ak >> 5;
    const int a_off  = ak & 15;
    uint8_t* awp[2] = { &Af[0][a_ks][a_lane * 16 + a_off],
                        &Af[1][a_ks][a_lane * 16 + a_off] };
    const float* xrow = x + (size_t)(row0 + ar) * KDIM + ak;
    const uint8_t* bbase = Wb2 + ((size_t)(wv * 2) * 2 * 64 + l) * 16;

    v16i acc0, acc1;
    #pragma unroll
    for (int e = 0; e < 16; ++e) { acc0[e] = 0; acc1[e] = 0; }

    float4 xp0, xp1;
    v4i bp0[4], bp1[4];

    // ---- prologue: A(0) -> Af[0]; xp1 := x(1); bp1 := B(0) ----
    {
        float4 x0 = *reinterpret_cast<const float4*>(xrow);
        xp1 = *reinterpret_cast<const float4*>(xrow + KSTEP);
        bp1[0] = *reinterpret_cast<const v4i*>(bbase);
        bp1[1] = *reinterpret_cast<const v4i*>(bbase + 1024);
        bp1[2] = *reinterpret_cast<const v4i*>(bbase + 2048);
        bp1[3] = *reinterpret_cast<const v4i*>(bbase + 3072);
        *reinterpret_cast<uint32_t*>(awp[0]) = sgn4(x0);
        __syncthreads();
    }

    #pragma unroll 1
    for (int s = 0; s < NSTEP; s += 2) {
        MMSTEP(s,     0, xp0, xp1, bp0, bp1);   // even: read Af[0], write Af[1]
        MMSTEP(s + 1, 1, xp1, xp0, bp1, bp0);   // odd : read Af[1], write Af[0]
    }

    // ---- epilogue: C = acc + bias (verified C/D map) ----
    #pragma unroll
    for (int ct = 0; ct < 2; ++ct) {
        const int col = wv * 64 + ct * 32 + lr;
        const float bv = bias[col];
        const v16i& a = ct ? acc1 : acc0;
        #pragma unroll
        for (int r = 0; r < 16; ++r) {
            int row = row0 + (r & 3) + 8 * (r >> 2) + 4 * hi;
            C[(size_t)row * UNITS + col] = (float)a[r] + bv;
        }
    }
}

extern "C" void kernel_launch(void* const* d_in, const int* in_sizes, int n_in,
                              void* d_out, int out_size, void* d_ws, size_t ws_size,
                              hipStream_t stream) {
    const float* x = (const float*)d_in[0];
    const float* W = (const float*)d_in[1];
    const float* b = (const float*)d_in[2];
    float* out = (float*)d_out;

    uint8_t* Wb2 = (uint8_t*)d_ws;   // 2 MB fragment-major packed W

    pack_w_kernel<<<(512 * 512) / 256, 256, 0, stream>>>(W, Wb2);
    mm_kernel<<<BATCH / MROWS, 512, 0, stream>>>(x, Wb2, b, out);
}

// Round 15
// 94.913 us; speedup vs baseline: 1.2284x; 1.0370x over previous
//
#include <hip/hip_runtime.h>
#include <stdint.h>

// Binarized dense via i8 MFMA: C[r][u] = dot(sign(x[r,:]), sign(W[:,u])) + b[u]
// sign in {+1,-1} as i8 0x01/0xFF; i32 accumulation exact (|dot| <= 4096).
// v_mfma_i32_32x32x32_i8: A/B = v4i (16 i8), lane&31 = row/col, lane>>5 =
// k-16-half; C/D: col = lane&31, row = (r&3)+8*(r>>2)+4*(lane>>5).
// All layouts/maps HW-verified (rounds 12-14, absmax 0).
//
// v10 = v9 with QUAD-STEP barrier periods (the round-14 stall fix):
// hipcc drains vmcnt(0) before every s_barrier; v9 issued x (HBM ~900cy)
// ~150cy before each of 64 barriers -> ~700cy exposed stall per step.
// Now: 16 periods x 4 K-steps. All 4 x-loads issue at period TOP and are
// committed (sgn4 -> LDS) before the period-END barrier, so the forced
// drain finds nothing young in flight (pending B was issued ~580cy earlier,
// L2 ~300cy). B uses 2 named register sets rotating load<->consume one
// MFMA-cluster apart (no copies, no runtime-indexed arrays).
//  - B never touches LDS: Wb2 fragment-major, wave loads = coalesced 1KB
//    dwordx4 from L2 (2MB resident), step stride 32KB.
//  - LDS = A-frags only: Af[2 bufs][8 frags][1024B] = 16 KB.
//  - 512 blocks x 512 thr (block = 32 rows x 512 cols, x read from HBM
//    exactly once), 2 blocks/CU. VGPR ~105 (acc32+bp32+xq16+af8+addr).

#define BATCH  16384
#define UNITS  512
#define KDIM   4096
#define KSTEP  64
#define NSTEP  (KDIM / KSTEP)   // 64
#define NPER   (NSTEP / 4)      // 16 quad-periods
#define MROWS  32               // rows per block

typedef int v4i  __attribute__((ext_vector_type(4)));
typedef int v16i __attribute__((ext_vector_type(16)));

// ---- pack W: f32 [4096][512] -> Wb2 fragment-major i8 +/-1 (2 MB) ----------
// 16B chunk index ((s*16 + n5)*2 + ks)*64 + lane; lane = (n&31) + 32*k16half;
// covers col n5*32+(n&31), k = s*64 + ks*32 + k16half*16 + [0..15].
__global__ __launch_bounds__(256) void pack_w_kernel(const float* __restrict__ W,
                                                     uint8_t* __restrict__ Wb2) {
    int t  = blockIdx.x * 256 + threadIdx.x;   // 0..262143
    int n  = t & 511;                          // col
    int k0 = (t >> 9) * 8;                     // 8 consecutive k
    unsigned long long m = 0;
    #pragma unroll
    for (int j = 0; j < 8; ++j) {
        float v = W[(size_t)(k0 + j) * UNITS + n];
        m |= ((v < 0.f) ? 0xFFull : 0x01ull) << (8 * j);
    }
    int s  = k0 >> 6;
    int kk = k0 & 63;
    int ks = kk >> 5;
    int hi = (kk & 31) >> 4;
    int lane = (n & 31) + 32 * hi;
    size_t a = ((((size_t)s * 16 + (n >> 5)) * 2 + ks) * 64 + lane) * 16 + (kk & 15);
    *reinterpret_cast<unsigned long long*>(Wb2 + a) = m;
}

__device__ __forceinline__ uint32_t sgn4(float4 v) {
    uint32_t b0 = v.x < 0.f ? 0xFFu : 0x01u;
    uint32_t b1 = v.y < 0.f ? 0xFFu : 0x01u;
    uint32_t b2 = v.z < 0.f ? 0xFFu : 0x01u;
    uint32_t b3 = v.w < 0.f ? 0xFFu : 0x01u;
    return b0 | (b1 << 8) | (b2 << 16) | (b3 << 24);
}

// load one step's 4 B-fragments (ct0ks0, ct0ks1, ct1ks0, ct1ks1)
#define LOADB(D0, D1, D2, D3, S)                                               \
    {                                                                          \
        const uint8_t* _b = bbase + (size_t)(S) * 32768;                       \
        D0 = *reinterpret_cast<const v4i*>(_b);                                \
        D1 = *reinterpret_cast<const v4i*>(_b + 1024);                         \
        D2 = *reinterpret_cast<const v4i*>(_b + 2048);                         \
        D3 = *reinterpret_cast<const v4i*>(_b + 3072);                         \
    }

// one K-step's MFMA cluster: A-frags FI0/FI1 of buffer PB, B regs B0..B3
#define CLUSTER(PB, FI0, FI1, B0, B1, B2, B3)                                  \
    {                                                                          \
        v4i af0 = *reinterpret_cast<const v4i*>(&Af[(PB) * 8192 + (FI0) * 1024 + l * 16]); \
        v4i af1 = *reinterpret_cast<const v4i*>(&Af[(PB) * 8192 + (FI1) * 1024 + l * 16]); \
        __builtin_amdgcn_s_setprio(1);                                         \
        acc0 = __builtin_amdgcn_mfma_i32_32x32x32_i8(af0, B0, acc0, 0, 0, 0);  \
        acc0 = __builtin_amdgcn_mfma_i32_32x32x32_i8(af1, B1, acc0, 0, 0, 0);  \
        acc1 = __builtin_amdgcn_mfma_i32_32x32x32_i8(af0, B2, acc1, 0, 0, 0);  \
        acc1 = __builtin_amdgcn_mfma_i32_32x32x32_i8(af1, B3, acc1, 0, 0, 0);  \
        __builtin_amdgcn_s_setprio(0);                                         \
    }

// one quad-period: steps 4Q..4Q+3 read Af[PB]; commits A(4Q+4..+7) -> Af[PB^1]
#define PERIOD(Q, PB)                                                          \
    {                                                                          \
        const int _s4 = 4 * (Q) + 4;                                           \
        float4 xq0 = *reinterpret_cast<const float4*>(                         \
            xrow + (size_t)((_s4     < NSTEP) ? _s4     : NSTEP - 1) * KSTEP); \
        float4 xq1 = *reinterpret_cast<const float4*>(                         \
            xrow + (size_t)((_s4 + 1 < NSTEP) ? _s4 + 1 : NSTEP - 1) * KSTEP); \
        float4 xq2 = *reinterpret_cast<const float4*>(                         \
            xrow + (size_t)((_s4 + 2 < NSTEP) ? _s4 + 2 : NSTEP - 1) * KSTEP); \
        float4 xq3 = *reinterpret_cast<const float4*>(                         \
            xrow + (size_t)((_s4 + 3 < NSTEP) ? _s4 + 3 : NSTEP - 1) * KSTEP); \
        LOADB(bp1a, bp1b, bp1c, bp1d, 4 * (Q) + 1);                            \
        CLUSTER(PB, 0, 1, bp0a, bp0b, bp0c, bp0d);                             \
        LOADB(bp0a, bp0b, bp0c, bp0d, 4 * (Q) + 2);                            \
        CLUSTER(PB, 2, 3, bp1a, bp1b, bp1c, bp1d);                             \
        LOADB(bp1a, bp1b, bp1c, bp1d, 4 * (Q) + 3);                            \
        CLUSTER(PB, 4, 5, bp0a, bp0b, bp0c, bp0d);                             \
        LOADB(bp0a, bp0b, bp0c, bp0d, (_s4 < NSTEP) ? _s4 : NSTEP - 1);        \
        CLUSTER(PB, 6, 7, bp1a, bp1b, bp1c, bp1d);                             \
        uint8_t* _aw = afw + ((PB) ^ 1) * 8192;                                \
        *reinterpret_cast<uint32_t*>(_aw)        = sgn4(xq0);                  \
        *reinterpret_cast<uint32_t*>(_aw + 2048) = sgn4(xq1);                  \
        *reinterpret_cast<uint32_t*>(_aw + 4096) = sgn4(xq2);                  \
        *reinterpret_cast<uint32_t*>(_aw + 6144) = sgn4(xq3);                  \
        __syncthreads();                                                       \
    }

// ------------------------------- MFMA GEMM ----------------------------------
__global__ __launch_bounds__(512, 1) void mm_kernel(const float* __restrict__ x,
                                                    const uint8_t* __restrict__ Wb2,
                                                    const float* __restrict__ bias,
                                                    float* __restrict__ C) {
    __shared__ __attribute__((aligned(16))) uint8_t Af[2 * 8 * 1024];  // 16 KB
    const int t   = threadIdx.x;
    const int l   = t & 63;
    const int wv  = t >> 6;              // wave 0..7 -> cols wv*64..+63
    const int lr  = l & 31;
    const int hi  = l >> 5;
    const int row0 = blockIdx.x * MROWS;
    // A staging: thread t owns row ar, float4 at k-offset ak of each step
    const int ar = t >> 4;               // 0..31
    const int ak = (t & 15) * 4;         // 0..60
    const int a_lane = (ar & 31) + 32 * ((ak >> 4) & 1);
    const int a_ks   = ak >> 5;
    const int a_off  = ak & 15;
    // commit base: frag (e*2 + a_ks) of buffer B at afw + B*8192 + e*2048
    uint8_t* afw = &Af[a_ks * 1024 + a_lane * 16 + a_off];
    const float* xrow = x + (size_t)(row0 + ar) * KDIM + ak;
    const uint8_t* bbase = Wb2 + ((size_t)(wv * 2) * 2 * 64 + l) * 16;

    v16i acc0, acc1;
    #pragma unroll
    for (int e = 0; e < 16; ++e) { acc0[e] = 0; acc1[e] = 0; }

    v4i bp0a, bp0b, bp0c, bp0d, bp1a, bp1b, bp1c, bp1d;

    // ---- prologue: commit A(0..3) -> Af[0]; bp0 <- B(0); barrier ----
    {
        float4 x0 = *reinterpret_cast<const float4*>(xrow);
        float4 x1 = *reinterpret_cast<const float4*>(xrow + KSTEP);
        float4 x2 = *reinterpret_cast<const float4*>(xrow + 2 * KSTEP);
        float4 x3 = *reinterpret_cast<const float4*>(xrow + 3 * KSTEP);
        LOADB(bp0a, bp0b, bp0c, bp0d, 0);
        *reinterpret_cast<uint32_t*>(afw)        = sgn4(x0);
        *reinterpret_cast<uint32_t*>(afw + 2048) = sgn4(x1);
        *reinterpret_cast<uint32_t*>(afw + 4096) = sgn4(x2);
        *reinterpret_cast<uint32_t*>(afw + 6144) = sgn4(x3);
        __syncthreads();
    }

    #pragma unroll 1
    for (int q = 0; q < NPER; q += 2) {
        PERIOD(q,     0);
        PERIOD(q + 1, 1);
    }

    // ---- epilogue: C = acc + bias (verified C/D map) ----
    #pragma unroll
    for (int ct = 0; ct < 2; ++ct) {
        const int col = wv * 64 + ct * 32 + lr;
        const float bv = bias[col];
        const v16i& a = ct ? acc1 : acc0;
        #pragma unroll
        for (int r = 0; r < 16; ++r) {
            int row = row0 + (r & 3) + 8 * (r >> 2) + 4 * hi;
            C[(size_t)row * UNITS + col] = (float)a[r] + bv;
        }
    }
}

extern "C" void kernel_launch(void* const* d_in, const int* in_sizes, int n_in,
                              void* d_out, int out_size, void* d_ws, size_t ws_size,
                              hipStream_t stream) {
    const float* x = (const float*)d_in[0];
    const float* W = (const float*)d_in[1];
    const float* b = (const float*)d_in[2];
    float* out = (float*)d_out;

    uint8_t* Wb2 = (uint8_t*)d_ws;   // 2 MB fragment-major packed W

    pack_w_kernel<<<(512 * 512) / 256, 256, 0, stream>>>(W, Wb2);
    mm_kernel<<<BATCH / MROWS, 512, 0, stream>>>(x, Wb2, b, out);
}